// Round 1
// baseline (234.242 us; speedup 1.0000x reference)
//
#include <hip/hip_runtime.h>

// Problem: b=1, m=128 variants, n=256 positions, c=22 classes.
// motifs[m,i,c] = ei[i,c] + sum_j eij[i,j,c,v[m,j]] * mask_vec[v[m,j]]
// logits[m,i]  = motifs[m,i,v[m,i]];  vl[m] = sigma * sum_i (logits[m,i]-logits[0,i])*vm
#define NC    22
#define NI    256
#define NJ    256
#define NM    128
#define JG    8              // j's per superstep
#define NSS   (NJ/JG)        // 32 supersteps -> all 256 j in ONE block (fused reduce)
#define SLOT  512            // f32 per staged j: 484 data + 28 zero pad (d-overrun reads)
#define MOTLD 23             // padded row stride of LDS motif accumulator

typedef __attribute__((ext_vector_type(8))) short short8;  // bf16x8 MFMA A/B frag
typedef __attribute__((ext_vector_type(4))) float f32x4;   // fp32x4 C/D frag

__device__ __forceinline__ uint32_t bf16rne(float x) {     // fp32 -> bf16 bits (RNE)
    uint32_t u = __float_as_uint(x);
    u += 0x7FFFu + ((u >> 16) & 1u);
    return u >> 16;
}

__device__ __forceinline__ uint32_t pk_bf16(float lo, float hi) {
    uint32_t r;
    asm("v_cvt_pk_bf16_f32 %0, %1, %2" : "=v"(r) : "v"(lo), "v"(hi));
    return r;
}

// Async global->LDS, 16 B per lane. Global addr is PER-LANE (gather ok);
// LDS dest is wave-uniform base + lane*16 (m104/m173 semantics).
__device__ __forceinline__ void gload_lds16(const void* g, void* l) {
    __builtin_amdgcn_global_load_lds(
        (const __attribute__((address_space(1))) void*)g,
        (__attribute__((address_space(3))) void*)l, 16, 0, 0);
}

union u32x4s8 { uint32_t u[4]; short8 s; };

// One block per i (256 blocks, 1024 thr = 16 waves = 4/SIMD, 1 block/CU).
// Wave w: j-slot jl=w>>1 (j == jl mod 8 across supersteps), m-half mh=w&1.
// Per superstep each wave: 1 async eij instr (1 KB), 1 j of compute:
// 2 B-frags (f32 LDS -> cvt_pk bf16) x 4 A-frags (one-hot * bf16(mask)) = 8 MFMA.
// Mask folded into A: A[m][d=v] = bf16(mask_vec[v]) -- identical algebra since
// em[i,j,c,d]*onehot(d=v) sums only d=v terms.
__global__ __launch_bounds__(1024) void potts_fused(
    const int*   __restrict__ variant,   // [128,256] int32
    const float* __restrict__ eij,       // [256,256,22,22]
    const float* __restrict__ ei,        // [256,22]
    const float* __restrict__ mask_vec,  // [22]
    float*       __restrict__ out_motifs,// [128,256,22]
    float*       __restrict__ out_logits)// [128,256]
{
    const int i    = blockIdx.x;
    const int tid  = threadIdx.x;
    const int lane = tid & 63;
    const int w    = tid >> 6;          // wave 0..15
    const int jl   = w >> 1;            // j slot 0..7
    const int mh   = w & 1;             // m half 0..1
    const int q    = lane >> 4;         // k-quad / row-quad
    const int nl   = lane & 15;         // frag row/col
    const int c1   = 16 + nl;

    __shared__ float    tile[2][JG][SLOT];   // 32 KB raw f32 eij slots (dbuf)
    __shared__ int      vtab[2][NM * JG];    // 8 KB  v[m][jl] (dbuf), async-staged
    __shared__ uint32_t maskTab[32];         // bf16 bits of mask_vec (pad->0)

    // One-time init: mask table + slot pads (floats 484..511). Pads are read
    // as B[k>=~22][c=21] by q=3 lanes; async never writes there -> keep 0
    // forever (0 * A(=0 at d>=22) avoids NaN and is exact).
    if (tid < 32) maskTab[tid] = (tid < NC) ? bf16rne(mask_vec[tid]) : 0u;
    if (tid < 2 * JG * (SLOT - 484)) {       // 448 pad floats
        const int b = tid / (JG * 28), r = tid % (JG * 28);
        tile[b][r / 28][484 + (r % 28)] = 0.f;
    }

    // eij staging: slot jl split in two 1 KB-ish halves by mh:
    //   part0: floats 0..255, part1: floats 228..483 (union=0..483, overlap
    //   228..255 written twice with identical data -> benign; NO global
    //   overshoot past the j block ever).
    const int    poff  = mh ? 228 : 0;                      // floats
    const size_t ebase = ((size_t)i * NJ + jl) * 484 + poff + lane * 4;
    // variant staging (4 KB/superstep): waves 8,10,12,14, per-lane 16 B gather
    // lane l -> m = pidx*32 + (l>>1), j-quad = (l&1)*4 => LDS layout [m][jl].
    const bool vstage = (w >= 8) && ((w & 1) == 0);
    const int  pidx   = (w - 8) >> 1;                       // 0..3
    const int  vmrow  = (pidx * 32 + (lane >> 1)) * NJ + (lane & 1) * 4;

    // Prologue: issue superstep 0 asyncs (drained by first __syncthreads).
    gload_lds16(eij + ebase, &tile[0][jl][poff]);
    if (vstage) gload_lds16(variant + vmrow, &vtab[0][pidx * 256]);

    f32x4 acc[4][2];
    #pragma unroll
    for (int mt = 0; mt < 4; ++mt) {
        acc[mt][0] = (f32x4){0.f, 0.f, 0.f, 0.f};
        acc[mt][1] = (f32x4){0.f, 0.f, 0.f, 0.f};
    }

    for (int s = 0; s < NSS; ++s) {
        const int cur = s & 1;
        // Barrier semantics (compiler emits s_waitcnt vmcnt(0) before
        // s_barrier): (a) this wave's async(s) landed, all waves synced ->
        // tile/vtab[cur] complete; (b) every wave finished compute(s-1), so
        // issuing async(s+1) into buffer cur^1 AFTER this barrier is race-free.
        __syncthreads();
        if (s + 1 < NSS) {
            const int nxt = cur ^ 1;
            gload_lds16(eij + ebase + (size_t)(s + 1) * (JG * 484),
                        &tile[nxt][jl][poff]);
            if (vstage)
                gload_lds16(variant + vmrow + (s + 1) * JG,
                            &vtab[nxt][pidx * 256]);
        }

        // ---- compute j = s*8 + jl for m rows mh*64 .. mh*64+63 ----
        // B-frag lane(q,nl): row c, floats c*22 + q*8 .. +7 (8B-aligned b64s;
        // distinct chunks across the wave -> mild <=4-way bank aliasing).
        const float* jrow = &tile[cur][jl][0];
        const float* r0 = jrow + nl * NC + q * 8;
        const float* r1 = jrow + (c1 < NC ? c1 : 0) * NC + q * 8;
        const float2 x0 = *(const float2*)(r0 + 0);
        const float2 x1 = *(const float2*)(r0 + 2);
        const float2 x2 = *(const float2*)(r0 + 4);
        const float2 x3 = *(const float2*)(r0 + 6);
        const float2 y0 = *(const float2*)(r1 + 0);
        const float2 y1 = *(const float2*)(r1 + 2);
        const float2 y2 = *(const float2*)(r1 + 4);
        const float2 y3 = *(const float2*)(r1 + 6);
        u32x4s8 B0, B1;
        B0.u[0] = pk_bf16(x0.x, x0.y);  B0.u[1] = pk_bf16(x1.x, x1.y);
        B0.u[2] = pk_bf16(x2.x, x2.y);  B0.u[3] = pk_bf16(x3.x, x3.y);
        B1.u[0] = pk_bf16(y0.x, y0.y);  B1.u[1] = pk_bf16(y1.x, y1.y);
        B1.u[2] = pk_bf16(y2.x, y2.y);  B1.u[3] = pk_bf16(y3.x, y3.y);

        const int* vt = vtab[cur];
        const int  kb = q * 4;
        #pragma unroll
        for (int mt = 0; mt < 4; ++mt) {
            const int      va = vt[(mh * 64 + mt * 16 + nl) * JG + jl] & 31;
            const uint32_t pa = maskTab[va] << ((va & 1) << 4);
            const int      ha = va >> 1;
            u32x4s8 A;
            #pragma unroll
            for (int t = 0; t < 4; ++t) A.u[t] = (ha == kb + t) ? pa : 0u;
            acc[mt][0] = __builtin_amdgcn_mfma_f32_16x16x32_bf16(A.s, B0.s, acc[mt][0], 0, 0, 0);
            acc[mt][1] = __builtin_amdgcn_mfma_f32_16x16x32_bf16(A.s, B1.s, acc[mt][1], 0, 0, 0);
        }
    }

    // ---- fused epilogue: 8-way jl reduction via LDS f32 atomics ----
    __syncthreads();                         // all compute done; reuse tile
    float* mot = &tile[0][0][0];             // [128][MOTLD] = 11.5 KB
    for (int p = tid; p < NM * MOTLD; p += 1024) mot[p] = 0.f;
    __syncthreads();
    // C/D layout (m89-verified): col = lane&15, row = (lane>>4)*4 + t.
    #pragma unroll
    for (int mt = 0; mt < 4; ++mt) {
        #pragma unroll
        for (int t = 0; t < 4; ++t) {
            const int row = mh * 64 + mt * 16 + q * 4 + t;
            atomicAdd(&mot[row * MOTLD + nl], acc[mt][0][t]);
            if (c1 < NC) atomicAdd(&mot[row * MOTLD + c1], acc[mt][1][t]);
        }
    }
    __syncthreads();
    const float* eirow = ei + i * NC;
    for (int p = tid; p < NM * 32; p += 1024) {
        const int m = p >> 5, c = p & 31;
        if (c < NC)
            out_motifs[((size_t)m * NI + i) * NC + c] = mot[m * MOTLD + c] + eirow[c];
    }
    if (tid < NM) {
        const int vi = variant[tid * NJ + i];
        out_logits[tid * NI + i] = mot[tid * MOTLD + vi] + eirow[vi];
    }
}

// variant_logit[m] = sigma * sum_i (logits[m,i]-logits[0,i]) * vm[m,i]*vm[0,i]
__global__ __launch_bounds__(64) void potts_pool(
    const float* __restrict__ logits,  // [128,256]
    const float* __restrict__ vmask,   // [128,256]
    const float* __restrict__ sigma,   // [1]
    float*       __restrict__ out_vl)  // [128]
{
    const int m    = blockIdx.x;
    const int lane = threadIdx.x;
    float s = 0.f;
    #pragma unroll
    for (int qq = 0; qq < 4; ++qq) {
        const int i = lane + 64 * qq;
        const float vl = logits[m * NI + i] - logits[i];
        s += vl * vmask[m * NI + i] * vmask[i];
    }
    #pragma unroll
    for (int off = 32; off > 0; off >>= 1)
        s += __shfl_down(s, off, 64);
    if (lane == 0) out_vl[m] = sigma[0] * s;
}

extern "C" void kernel_launch(void* const* d_in, const int* in_sizes, int n_in,
                              void* d_out, int out_size, void* d_ws, size_t ws_size,
                              hipStream_t stream) {
    const int*   variant  = (const int*)  d_in[0];  // [1,128,256] int32
    const float* vmask    = (const float*)d_in[1];  // [1,128,256]
    const float* eij      = (const float*)d_in[2];  // [1,256,256,22,22]
    const float* ei       = (const float*)d_in[3];  // [1,256,22]
    const float* mask_vec = (const float*)d_in[4];  // [22]
    const float* sigma    = (const float*)d_in[5];  // [1]

    float* out        = (float*)d_out;
    float* out_motifs = out;                        // 128*256*22
    float* out_logits = out_motifs + NM * NI * NC;  // 128*256
    float* out_vl     = out_logits + NM * NI;       // 128

    potts_fused<<<NI, 1024, 0, stream>>>(variant, eij, ei, mask_vec,
                                         out_motifs, out_logits);
    potts_pool<<<NM, 64, 0, stream>>>(out_logits, vmask, sigma, out_vl);
}